// Round 13
// baseline (114.210 us; speedup 1.0000x reference)
//
#include <hip/hip_runtime.h>

// out[b,c,t] = events[b,c,t-d_c] if t >= d_c else 0
// d_c = argmax_j(pos[c,j]) * 64   (first occurrence; softmax is monotone)
#define N_SAMPLES 65536
#define POS_LEN   1024
#define STEP      64
#define NCH       32
#define NB        8
#define ROW4      (N_SAMPLES / 4)    // 16384 float4 per row
#define SEGS      8                  // blocks per row
#define SEG4      (ROW4 / SEGS)      // 2048 float4 per block

typedef float f32x4 __attribute__((ext_vector_type(4)));

// Kernel 1: one wave per channel, first-occurrence argmax over 1024 floats.
// Writes the delay in float4 units (multiple of 16) to d_ws.
__global__ __launch_bounds__(64) void argmax32(const float* __restrict__ pos,
                                               int* __restrict__ delay4) {
    const int c    = blockIdx.x;       // 0..31
    const int lane = threadIdx.x;      // 0..63
    const f32x4* row = (const f32x4*)(pos + c * POS_LEN);  // 256 float4

    // 64 lanes x 4 float4 = 1024 floats, coalesced
    float best = -__builtin_inff();
    int   bidx = POS_LEN;              // sentinel, never wins ties
    #pragma unroll
    for (int k = 0; k < 4; ++k) {
        const int  e = k * 64 + lane;  // float4 index
        const f32x4 v = row[e];
        #pragma unroll
        for (int j = 0; j < 4; ++j) {
            const int idx = e * 4 + j;
            // strict '>' keeps earliest index; iterate in increasing idx order
            if (v[j] > best) { best = v[j]; bidx = idx; }
        }
    }
    #pragma unroll
    for (int off = 32; off > 0; off >>= 1) {
        float ov = __shfl_down(best, off, 64);
        int   oi = __shfl_down(bidx, off, 64);
        if (ov > best || (ov == best && oi < bidx)) { best = ov; bidx = oi; }
    }
    if (lane == 0) delay4[c] = bidx * (STEP / 4);
}

// Kernel 2: pure stream. One block = one (row, segment); prologue is a single
// uniform scalar load of delay4[c]. Zero-fill and copy regions are separate
// branch-free loops; plain cached float4 ld/st (nt measured -5us in R7/R10).
__global__ __launch_bounds__(256) void dirac_shift(const f32x4* __restrict__ in,
                                                   f32x4* __restrict__ out,
                                                   const int* __restrict__ delay4) {
    const int g   = blockIdx.x;           // 0..2047
    const int row = g >> 3;               // 0..255  (= b*32 + c)
    const int seg = g & (SEGS - 1);
    const int c   = row & (NCH - 1);
    const int tid = threadIdx.x;          // 0..255

    const int d4   = delay4[c];           // uniform -> scalar load
    const int base = seg * SEG4;
    const int end  = base + SEG4;
    const f32x4* inrow  = in  + (size_t)row * ROW4;
    f32x4*       outrow = out + (size_t)row * ROW4;

    // zero-fill [base, min(end, d4))
    const int zhi = d4 < end ? d4 : end;
    const f32x4 zero = {0.f, 0.f, 0.f, 0.f};
    for (int t4 = base + tid; t4 < zhi; t4 += 256) {
        outrow[t4] = zero;
    }

    // copy [max(base, d4), end):  out[t4] = in[t4 - d4]
    const int clo = d4 > base ? d4 : base;
    #pragma unroll 4
    for (int t4 = clo + tid; t4 < end; t4 += 256) {
        outrow[t4] = inrow[t4 - d4];
    }
}

extern "C" void kernel_launch(void* const* d_in, const int* in_sizes, int n_in,
                              void* d_out, int out_size, void* d_ws, size_t ws_size,
                              hipStream_t stream) {
    const float* events = (const float*)d_in[0];   // (8,32,65536)
    const float* pos    = (const float*)d_in[1];   // (1,32,1024)
    float*       out    = (float*)d_out;           // (8,32,65536)
    int*         delay4 = (int*)d_ws;              // 32 ints scratch

    argmax32<<<NCH, 64, 0, stream>>>(pos, delay4);
    dirac_shift<<<NB * NCH * SEGS, 256, 0, stream>>>((const f32x4*)events, (f32x4*)out, delay4);
}